// Round 5
// baseline (4580.028 us; speedup 1.0000x reference)
//
#include <hip/hip_runtime.h>

typedef _Float16 half8 __attribute__((ext_vector_type(8)));
typedef _Float16 half4 __attribute__((ext_vector_type(4)));
typedef float floatx4 __attribute__((ext_vector_type(4)));
typedef unsigned uintx4 __attribute__((ext_vector_type(4)));
typedef unsigned long long u64;

#define T_STEPS 512
#define IN_DIM 256
#define HID 512

// ---- R9: tagged-word protocol ----
// h element = u32 (tag<<16)|fp16bits, tag(step s)=s+1 (seed s=-1 -> tag 0).
// Producers store fire-and-forget (no drain, no flags on the data path).
// Consumers poll the data itself: batch-load, min-reduce tags, retry.
// init stamps all slots to tag 0 each launch (graph-replay safe).
// h0 ring reuse throttled by per-wave progress flags (hidden polls).

__device__ inline float sig_f(float x) { return 1.f / (1.f + __expf(-x)); }
__device__ inline float tanh_f(float x) {
  float t = __expf(-2.f * fabsf(x));
  return copysignf((1.f - t) / (1.f + t), x);
}
__device__ inline unsigned umin_(unsigned a, unsigned b) { return a < b ? a : b; }

// Tagged u64 store: two adjacent tagged cols, fire-and-forget, agent scope.
__device__ inline void tstore2(unsigned* p, unsigned tghi, float a, float b) {
  unsigned lo = tghi | (unsigned)__builtin_bit_cast(unsigned short, (_Float16)a);
  unsigned hi = tghi | (unsigned)__builtin_bit_cast(unsigned short, (_Float16)b);
  u64 d = ((u64)hi << 32) | lo;
  __hip_atomic_store((u64*)p, d, __ATOMIC_RELAXED, __HIP_MEMORY_SCOPE_AGENT);
}

// 32x16B tagged loads (one row-half of 512 tagged cols per lane-group),
// issued back-to-back, one waitcnt. Offsets: frag c at bytes 128c, 128c+16.
#define TL16A                                                   \
  "global_load_dwordx4 %0, %16, off sc0 sc1\n\t"                \
  "global_load_dwordx4 %1, %16, off offset:16 sc0 sc1\n\t"      \
  "global_load_dwordx4 %2, %16, off offset:128 sc0 sc1\n\t"     \
  "global_load_dwordx4 %3, %16, off offset:144 sc0 sc1\n\t"     \
  "global_load_dwordx4 %4, %16, off offset:256 sc0 sc1\n\t"     \
  "global_load_dwordx4 %5, %16, off offset:272 sc0 sc1\n\t"     \
  "global_load_dwordx4 %6, %16, off offset:384 sc0 sc1\n\t"     \
  "global_load_dwordx4 %7, %16, off offset:400 sc0 sc1\n\t"     \
  "global_load_dwordx4 %8, %16, off offset:512 sc0 sc1\n\t"     \
  "global_load_dwordx4 %9, %16, off offset:528 sc0 sc1\n\t"     \
  "global_load_dwordx4 %10, %16, off offset:640 sc0 sc1\n\t"    \
  "global_load_dwordx4 %11, %16, off offset:656 sc0 sc1\n\t"    \
  "global_load_dwordx4 %12, %16, off offset:768 sc0 sc1\n\t"    \
  "global_load_dwordx4 %13, %16, off offset:784 sc0 sc1\n\t"    \
  "global_load_dwordx4 %14, %16, off offset:896 sc0 sc1\n\t"    \
  "global_load_dwordx4 %15, %16, off offset:912 sc0 sc1"
#define TL16B                                                   \
  "global_load_dwordx4 %0, %16, off offset:1024 sc0 sc1\n\t"    \
  "global_load_dwordx4 %1, %16, off offset:1040 sc0 sc1\n\t"    \
  "global_load_dwordx4 %2, %16, off offset:1152 sc0 sc1\n\t"    \
  "global_load_dwordx4 %3, %16, off offset:1168 sc0 sc1\n\t"    \
  "global_load_dwordx4 %4, %16, off offset:1280 sc0 sc1\n\t"    \
  "global_load_dwordx4 %5, %16, off offset:1296 sc0 sc1\n\t"    \
  "global_load_dwordx4 %6, %16, off offset:1408 sc0 sc1\n\t"    \
  "global_load_dwordx4 %7, %16, off offset:1424 sc0 sc1\n\t"    \
  "global_load_dwordx4 %8, %16, off offset:1536 sc0 sc1\n\t"    \
  "global_load_dwordx4 %9, %16, off offset:1552 sc0 sc1\n\t"    \
  "global_load_dwordx4 %10, %16, off offset:1664 sc0 sc1\n\t"   \
  "global_load_dwordx4 %11, %16, off offset:1680 sc0 sc1\n\t"   \
  "global_load_dwordx4 %12, %16, off offset:1792 sc0 sc1\n\t"   \
  "global_load_dwordx4 %13, %16, off offset:1808 sc0 sc1\n\t"   \
  "global_load_dwordx4 %14, %16, off offset:1920 sc0 sc1\n\t"   \
  "global_load_dwordx4 %15, %16, off offset:1936 sc0 sc1"

// Poll-load one tagged row-half (128 tagged u32 per lane) until all tags
// match exp, then unpack to 16 MFMA A-fragments. Per-wave independent.
// Tag check at u64 granularity (words 0,2 of each dwordx4: producer stores
// are 8B-atomic units). min>=exp<<16 is exact: tags monotone within a poll.
__device__ inline void tagpoll16(const unsigned* base, unsigned exp, half8 (&f)[16]) {
  const unsigned expw = exp << 16;
  uintx4 u[32];
  int it = 0;
  for (;;) {
    floatx4 t0, t1, t2, t3, t4, t5, t6, t7, t8, t9, t10, t11, t12, t13, t14, t15;
    floatx4 s0, s1, s2, s3, s4, s5, s6, s7, s8, s9, s10, s11, s12, s13, s14, s15;
    asm volatile(TL16A
                 : "=&v"(t0), "=&v"(t1), "=&v"(t2), "=&v"(t3),
                   "=&v"(t4), "=&v"(t5), "=&v"(t6), "=&v"(t7),
                   "=&v"(t8), "=&v"(t9), "=&v"(t10), "=&v"(t11),
                   "=&v"(t12), "=&v"(t13), "=&v"(t14), "=&v"(t15)
                 : "v"(base)
                 : "memory");
    asm volatile(TL16B "\n\t"
                 "s_waitcnt vmcnt(0)"
                 : "=&v"(s0), "=&v"(s1), "=&v"(s2), "=&v"(s3),
                   "=&v"(s4), "=&v"(s5), "=&v"(s6), "=&v"(s7),
                   "=&v"(s8), "=&v"(s9), "=&v"(s10), "=&v"(s11),
                   "=&v"(s12), "=&v"(s13), "=&v"(s14), "=&v"(s15)
                 : "v"(base)
                 : "memory");
    __builtin_amdgcn_sched_barrier(0);  // no consumer of t*/s* above the wait
    u[0] = __builtin_bit_cast(uintx4, t0);   u[1] = __builtin_bit_cast(uintx4, t1);
    u[2] = __builtin_bit_cast(uintx4, t2);   u[3] = __builtin_bit_cast(uintx4, t3);
    u[4] = __builtin_bit_cast(uintx4, t4);   u[5] = __builtin_bit_cast(uintx4, t5);
    u[6] = __builtin_bit_cast(uintx4, t6);   u[7] = __builtin_bit_cast(uintx4, t7);
    u[8] = __builtin_bit_cast(uintx4, t8);   u[9] = __builtin_bit_cast(uintx4, t9);
    u[10] = __builtin_bit_cast(uintx4, t10); u[11] = __builtin_bit_cast(uintx4, t11);
    u[12] = __builtin_bit_cast(uintx4, t12); u[13] = __builtin_bit_cast(uintx4, t13);
    u[14] = __builtin_bit_cast(uintx4, t14); u[15] = __builtin_bit_cast(uintx4, t15);
    u[16] = __builtin_bit_cast(uintx4, s0);  u[17] = __builtin_bit_cast(uintx4, s1);
    u[18] = __builtin_bit_cast(uintx4, s2);  u[19] = __builtin_bit_cast(uintx4, s3);
    u[20] = __builtin_bit_cast(uintx4, s4);  u[21] = __builtin_bit_cast(uintx4, s5);
    u[22] = __builtin_bit_cast(uintx4, s6);  u[23] = __builtin_bit_cast(uintx4, s7);
    u[24] = __builtin_bit_cast(uintx4, s8);  u[25] = __builtin_bit_cast(uintx4, s9);
    u[26] = __builtin_bit_cast(uintx4, s10); u[27] = __builtin_bit_cast(uintx4, s11);
    u[28] = __builtin_bit_cast(uintx4, s12); u[29] = __builtin_bit_cast(uintx4, s13);
    u[30] = __builtin_bit_cast(uintx4, s14); u[31] = __builtin_bit_cast(uintx4, s15);
    unsigned mn = 0xffffffffu;
#pragma unroll
    for (int k = 0; k < 32; ++k) {
      mn = umin_(mn, u[k].x);
      mn = umin_(mn, u[k].z);
    }
    if (__all((int)(mn >= expw))) break;
    if (++it > 3) __builtin_amdgcn_s_sleep(1);
  }
#pragma unroll
  for (int c = 0; c < 16; ++c) {
    unsigned q0 = (u[2 * c].x & 0xffffu) | (u[2 * c].y << 16);
    unsigned q1 = (u[2 * c].z & 0xffffu) | (u[2 * c].w << 16);
    unsigned q2 = (u[2 * c + 1].x & 0xffffu) | (u[2 * c + 1].y << 16);
    unsigned q3 = (u[2 * c + 1].z & 0xffffu) | (u[2 * c + 1].w << 16);
    uintx4 qq = {q0, q1, q2, q3};
    f[c] = __builtin_bit_cast(half8, qq);
  }
}

// Epilogue-only: lane i min-reduces block i's 4 per-wave sub-flags (16B).
__device__ inline void waitf4(const unsigned* fg, unsigned tg) {
  const unsigned* p = fg + (threadIdx.x & 63) * 32;
  int it = 0;
  for (;;) {
    floatx4 t;
    asm volatile("global_load_dwordx4 %0, %1, off sc0 sc1\n\t"
                 "s_waitcnt vmcnt(0)"
                 : "=&v"(t) : "v"(p) : "memory");
    uintx4 u = __builtin_bit_cast(uintx4, t);
    unsigned m = umin_(umin_(u.x, u.y), umin_(u.z, u.w));
    if (__all((int)(m >= tg))) return;
    if (++it > 4) __builtin_amdgcn_s_sleep(1);
  }
}

__device__ inline floatx4 mfma16(half8 a, half8 b, floatx4 c) {
  return __builtin_amdgcn_mfma_f32_16x16x32_f16(a, b, c, 0, 0, 0);
}

__global__ void init_kernel(const float* __restrict__ x, const float* __restrict__ hc,
                            _Float16* __restrict__ x16, unsigned* __restrict__ h0b,
                            unsigned* __restrict__ h1b, unsigned* __restrict__ flagbase) {
  size_t i = (size_t)blockIdx.x * blockDim.x + threadIdx.x;
  size_t stride = (size_t)gridDim.x * blockDim.x;
  const size_t n4 = (size_t)T_STEPS * 64 * IN_DIM / 4;
  const floatx4* xv = (const floatx4*)x;
  for (size_t idx = i; idx < n4; idx += stride) {
    floatx4 v = xv[idx];
    half4 h;
    h.x = (_Float16)v.x; h.y = (_Float16)v.y;
    h.z = (_Float16)v.z; h.w = (_Float16)v.w;
    *(half4*)(x16 + idx * 4) = h;
  }
  // Stamp ALL tagged h words to tag 0 (low halves = seeds where applicable).
  // h0b: 8*32768 u32 (seed slot 7 = h0[-1]); h1b: 2*32768 u32 (seed parity 1).
  const size_t ntag = 262144 + 65536;
  for (size_t idx = i; idx < ntag; idx += stride) {
    if (idx < 262144) {
      unsigned v = 0;
      if (idx >= 229376)  // slot 7: hc[0] block (layer-0 h seed)
        v = (unsigned)__builtin_bit_cast(unsigned short, (_Float16)hc[idx - 229376]);
      __hip_atomic_store(h0b + idx, v, __ATOMIC_RELAXED, __HIP_MEMORY_SCOPE_AGENT);
    } else {
      size_t j = idx - 262144;
      unsigned v = 0;
      if (j >= 32768)  // parity 1: hc[1] block (layer-1 h seed)
        v = (unsigned)__builtin_bit_cast(unsigned short, (_Float16)hc[j]);
      __hip_atomic_store(h1b + j, v, __ATOMIC_RELAXED, __HIP_MEMORY_SCOPE_AGENT);
    }
  }
  if (i < 4096) {  // zero both flag arrays (2 x 8192 B contiguous)
    __hip_atomic_store(flagbase + i, 0u, __ATOMIC_RELAXED, __HIP_MEMORY_SCOPE_AGENT);
  }
}

// R9: tagged-data protocol. Blocks 0..63 = L0, 64..127 = L1; 4 waves/block,
// wave w owns batch rows 16w..16w+15 end-to-end (wave-w-to-wave-w dependency
// closure across blocks). NO barriers, NO drains, NO flag RTTs in the loop.
// flags0/flags1 survive only as per-wave PROGRESS throttles for h0-ring reuse
// (polled with pre-issued loads hidden under L0's X phase).
__global__ __launch_bounds__(256, 1) void lstm_kernel(
    const _Float16* __restrict__ x16, unsigned* __restrict__ h0b, unsigned* __restrict__ h1b,
    unsigned* __restrict__ flags0, unsigned* __restrict__ flags1,
    const float* __restrict__ W_ih0, const float* __restrict__ W_hh0,
    const float* __restrict__ b_ih0, const float* __restrict__ b_hh0,
    const float* __restrict__ W_ih1, const float* __restrict__ W_hh1,
    const float* __restrict__ b_ih1, const float* __restrict__ b_hh1,
    const float* __restrict__ W_out, const float* __restrict__ b_out,
    const float* __restrict__ hc, float* __restrict__ out) {
  __shared__ __align__(16) _Float16 wlds[32 * 1032];

  const int bq = blockIdx.x;
  const bool isL0 = bq < 64;
  const int q = isL0 ? bq : bq - 64;
  const int col0 = q * 8;
  const int Ka = isL0 ? IN_DIM : HID;
  const int K = Ka + HID;
  const int WP = K + 8;
  const int layer = isL0 ? 0 : 1;
  const float* Wa = isL0 ? W_ih0 : W_ih1;
  const float* Wb = isL0 ? W_hh0 : W_hh1;
  const float* bia = isL0 ? b_ih0 : b_ih1;
  const float* bib = isL0 ? b_hh0 : b_hh1;

  for (int idx = threadIdx.x; idx < 32 * K; idx += 256) {
    int r = idx / K;
    int k = idx - r * K;
    int g = r >> 3, j = r & 7;
    int grow = g * HID + col0 + j;  // PyTorch gate order i,f,g,o
    float w = (k < Ka) ? Wa[(size_t)grow * Ka + k] : Wb[(size_t)grow * HID + (k - Ka)];
    wlds[r * WP + k] = (_Float16)w;
  }
  __syncthreads();

  const int lane = threadIdx.x & 63;
  const int wv = threadIdx.x >> 6;   // 0..3
  const int lrow = lane & 15;
  const int kq = (lane >> 4) * 8;
  const int m0 = wv * 16;
  const _Float16* wrow0 = wlds + lrow * WP;
  const _Float16* wrow1 = wlds + (16 + lrow) * WP;

  // Recurrent-half B fragments in registers/AGPRs (proven in R2/R3).
  half8 breg0[16], breg1[16];
#pragma unroll
  for (int c = 0; c < 16; ++c) {
    breg0[c] = *(const half8*)(wrow0 + Ka + c * 32 + kq);
    breg1[c] = *(const half8*)(wrow1 + Ka + c * 32 + kq);
  }

  // Register-gate-phase constants (R8-proven mapping).
  const int bsel = lrow >> 3;
  const int jc = lrow & 7;
  const int rbase = m0 + ((lane >> 4) << 2) + 2 * bsel;
  const int colg = col0 + jc;
  const float bi_ = bia[colg] + bib[colg];
  const float bf_ = bia[HID + colg] + bib[HID + colg];
  const float bg_ = bia[2 * HID + colg] + bib[2 * HID + colg];
  const float bo_ = bia[3 * HID + colg] + bib[3 * HID + colg];
  float cst0 = hc[(size_t)(2 + layer) * 32768 + (size_t)(rbase + 0) * HID + colg];
  float cst1 = hc[(size_t)(2 + layer) * 32768 + (size_t)(rbase + 1) * HID + colg];

  unsigned* myflag = (isL0 ? flags0 : flags1) + q * 32 + wv;
  const unsigned* pf0 = flags0 + lane * 32 + wv;  // L0 self-throttle gather
  const unsigned* pf1 = flags1 + lane * 32 + wv;  // ring throttle gather

  const size_t lrowoff = (size_t)(m0 + lrow) * 512 + kq;

  for (int t = 0; t < T_STEPS; ++t) {
    floatx4 acc0 = {0.f, 0.f, 0.f, 0.f};
    floatx4 acc1 = {0.f, 0.f, 0.f, 0.f};
    unsigned* dstu;
    half8 f[16];

    if (isL0) {
      // Pre-issue throttle flag loads; hide their RTT under the X phase.
      unsigned f0v = 0xffffffffu, f1v = 0xffffffffu;
      const bool chk = (t >= 7);
      if (chk) {
        asm volatile("global_load_dword %0, %2, off sc0 sc1\n\t"
                     "global_load_dword %1, %3, off sc0 sc1"
                     : "=&v"(f0v), "=&v"(f1v)
                     : "v"(pf0), "v"(pf1) : "memory");
      }
      // X phase (no cross-block dep).
      const _Float16* a0p = x16 + (size_t)t * (64 * IN_DIM) + (m0 + lrow) * IN_DIM + kq;
#pragma unroll
      for (int c = 0; c < 8; ++c) {
        half8 a = *(const half8*)(a0p + c * 32);
        half8 b0v = *(const half8*)(wrow0 + c * 32 + kq);
        half8 b1v = *(const half8*)(wrow1 + c * 32 + kq);
        acc0 = mfma16(a, b0v, acc0);
        acc1 = mfma16(a, b1v, acc1);
      }
      if (chk) {
        asm volatile("s_waitcnt vmcnt(0)" ::: "memory");
        __builtin_amdgcn_sched_barrier(0);
        // flags0 >= t-6: peers validated h0[t-8] (self-ring, lead <= 7).
        // flags1 >= t-7: L1 validated h0[t-8] (consumer-ring).
        const unsigned need0 = (unsigned)(t - 6);
        const unsigned need1 = (t >= 8) ? (unsigned)(t - 7) : 0u;
        int it = 0;
        while (!__all((int)((f0v >= need0) & (f1v >= need1)))) {
          if (++it > 2) __builtin_amdgcn_s_sleep(1);
          asm volatile("global_load_dword %0, %2, off sc0 sc1\n\t"
                       "global_load_dword %1, %3, off sc0 sc1\n\t"
                       "s_waitcnt vmcnt(0)"
                       : "=&v"(f0v), "=&v"(f1v)
                       : "v"(pf0), "v"(pf1) : "memory");
          __builtin_amdgcn_sched_barrier(0);
        }
      }
      // Recurrent phase: poll-load h0[t-1] (tag t), then MFMA.
      const unsigned* a1p = h0b + (size_t)((t - 1) & 7) * 32768 + lrowoff;
      tagpoll16(a1p, (unsigned)t, f);
      if (lane == 0)  // progress publish (validation, not stores -> no drain)
        __hip_atomic_store(myflag, (unsigned)(t + 1), __ATOMIC_RELAXED, __HIP_MEMORY_SCOPE_AGENT);
#pragma unroll
      for (int c = 0; c < 16; ++c) {
        acc0 = mfma16(f[c], breg0[c], acc0);
        acc1 = mfma16(f[c], breg1[c], acc1);
      }
      dstu = h0b + (size_t)(t & 7) * 32768;
    } else {
      // Phase 1: poll-load h0[t] (tag t+1); doubles as the data load.
      const unsigned* a0p = h0b + (size_t)(t & 7) * 32768 + lrowoff;
      tagpoll16(a0p, (unsigned)(t + 1), f);
      if (lane == 0)  // ring release: h0[t] consumed by this wave
        __hip_atomic_store(myflag, (unsigned)(t + 1), __ATOMIC_RELAXED, __HIP_MEMORY_SCOPE_AGENT);
#pragma unroll
      for (int c = 0; c < 16; ++c) {
        half8 b0v = *(const half8*)(wrow0 + c * 32 + kq);
        half8 b1v = *(const half8*)(wrow1 + c * 32 + kq);
        acc0 = mfma16(f[c], b0v, acc0);
        acc1 = mfma16(f[c], b1v, acc1);
      }
      // Phase 2: poll-load h1[t-1] (tag t) — THE recurrence hop.
      const unsigned* a1p = h1b + (size_t)((t - 1) & 1) * 32768 + lrowoff;
      tagpoll16(a1p, (unsigned)t, f);
#pragma unroll
      for (int c = 0; c < 16; ++c) {
        acc0 = mfma16(f[c], breg0[c], acc0);
        acc1 = mfma16(f[c], breg1[c], acc1);
      }
      dstu = h1b + (size_t)(t & 1) * 32768;
    }

    // ---- register gate phase (R8-proven) ----
    float s00 = __shfl_xor(bsel ? (float)acc0[0] : (float)acc0[2], 8);
    float s01 = __shfl_xor(bsel ? (float)acc0[1] : (float)acc0[3], 8);
    float s10 = __shfl_xor(bsel ? (float)acc1[0] : (float)acc1[2], 8);
    float s11 = __shfl_xor(bsel ? (float)acc1[1] : (float)acc1[3], 8);
    float hv0, hv1;
    {
      float o0 = bsel ? (float)acc0[2] : (float)acc0[0];
      float o1 = bsel ? (float)acc1[2] : (float)acc1[0];
      float gi = bsel ? s00 : o0;
      float gf = bsel ? o0 : s00;
      float gg = bsel ? s10 : o1;
      float go = bsel ? o1 : s10;
      float c = sig_f(gf + bf_) * cst0 + sig_f(gi + bi_) * tanh_f(gg + bg_);
      cst0 = c;
      hv0 = sig_f(go + bo_) * tanh_f(c);
    }
    {
      float o0 = bsel ? (float)acc0[3] : (float)acc0[1];
      float o1 = bsel ? (float)acc1[3] : (float)acc1[1];
      float gi = bsel ? s01 : o0;
      float gf = bsel ? o0 : s01;
      float gg = bsel ? s11 : o1;
      float go = bsel ? o1 : s11;
      float c = sig_f(gf + bf_) * cst1 + sig_f(gi + bi_) * tanh_f(gg + bg_);
      cst1 = c;
      hv1 = sig_f(go + bo_) * tanh_f(c);
    }
    float hx0 = __shfl_xor(hv0, 1);
    float hx1 = __shfl_xor(hv1, 1);
    if ((jc & 1) == 0) {
      const unsigned tghi = (unsigned)(t + 1) << 16;
      tstore2(dstu + (size_t)rbase * 512 + col0 + jc, tghi, hv0, hx0);
      tstore2(dstu + (size_t)(rbase + 1) * 512 + col0 + jc, tghi, hv1, hx1);
    }
    // Fire-and-forget: no drain, no flag, no barrier. Next step.
  }

  if (!isL0) {
    // Final-store sentinel for the epilogue (the one drain in the kernel).
    asm volatile("s_waitcnt vmcnt(0)" ::: "memory");
    if (lane == 0)
      __hip_atomic_store(myflag, 513u, __ATOMIC_RELAXED, __HIP_MEMORY_SCOPE_AGENT);
  } else {
    // Final linear: out[64,256] = h1[511] @ W_out^T + b_out.
    if (threadIdx.x < 64) waitf4(flags1, 513u);
    __syncthreads();
    asm volatile("" ::: "memory");
    const int oc = q * 4 + (threadIdx.x & 3);
    const int m = threadIdx.x >> 2;
    const unsigned* hrow = h1b + 32768 + m * 512;  // h1[511] at parity 1 (tagged)
    const float* wrow = W_out + (size_t)oc * HID;
    float sum = 0.f;
#pragma unroll 8
    for (int h = 0; h < HID; h += 2) {
      u64 d = __hip_atomic_load((const u64*)(hrow + h), __ATOMIC_RELAXED,
                                __HIP_MEMORY_SCOPE_AGENT);
      sum += (float)__builtin_bit_cast(_Float16, (unsigned short)(d & 0xffffu)) * wrow[h];
      sum += (float)__builtin_bit_cast(_Float16, (unsigned short)((d >> 32) & 0xffffu)) * wrow[h + 1];
    }
    out[m * 256 + oc] = sum + b_out[oc];
  }
}

extern "C" void kernel_launch(void* const* d_in, const int* in_sizes, int n_in,
                              void* d_out, int out_size, void* d_ws, size_t ws_size,
                              hipStream_t stream) {
  const float* x     = (const float*)d_in[0];
  const float* hc    = (const float*)d_in[1];
  const float* W_ih0 = (const float*)d_in[2];
  const float* W_hh0 = (const float*)d_in[3];
  const float* b_ih0 = (const float*)d_in[4];
  const float* b_hh0 = (const float*)d_in[5];
  const float* W_ih1 = (const float*)d_in[6];
  const float* W_hh1 = (const float*)d_in[7];
  const float* b_ih1 = (const float*)d_in[8];
  const float* b_hh1 = (const float*)d_in[9];
  const float* W_out = (const float*)d_in[10];
  const float* b_out = (const float*)d_in[11];
  float* out = (float*)d_out;

  char* ws = (char*)d_ws;
  _Float16* x16 = (_Float16*)ws;                         // 16 MB
  unsigned* h0b = (unsigned*)(ws + 16777216);            // 8 x 128 KB tagged ring
  unsigned* h1b = (unsigned*)(ws + 16777216 + 1048576);  // 2 x 128 KB tagged
  unsigned* flags0 = (unsigned*)(ws + 16777216 + 1048576 + 262144);         // 8 KB
  unsigned* flags1 = (unsigned*)(ws + 16777216 + 1048576 + 262144 + 8192);  // 8 KB

  init_kernel<<<2048, 256, 0, stream>>>(x, hc, x16, h0b, h1b, flags0);
  lstm_kernel<<<128, 256, 0, stream>>>(x16, h0b, h1b, flags0, flags1,
                                       W_ih0, W_hh0, b_ih0, b_hh0,
                                       W_ih1, W_hh1, b_ih1, b_hh1,
                                       W_out, b_out, hc, out);
}

// Round 6
// 1817.501 us; speedup vs baseline: 2.5200x; 2.5200x over previous
//
#include <hip/hip_runtime.h>

typedef _Float16 half8 __attribute__((ext_vector_type(8)));
typedef _Float16 half4 __attribute__((ext_vector_type(4)));
typedef float floatx4 __attribute__((ext_vector_type(4)));
typedef unsigned uintx4 __attribute__((ext_vector_type(4)));
typedef unsigned long long u64;

#define T_STEPS 512
#define IN_DIM 256
#define HID 512
#define RING 8

// ---- R10: R8 protocol (best, 2979us) + fragment-linear h/x layout ----
// Element (R,C) of a 64x512 h snapshot lives at byte:
//   (R>>4)*16384 + (C>>5)*1024 + ((R&15) + 16*((C>>3)&3))*16 + (C&7)*2
// == exactly the order consumer wave (R>>4)'s lanes read MFMA A-fragments.
// h-loads become 16 coalesced dwordx4 (4 cache lines each) instead of 32
// 64-line gathers: ~9x fewer LLC line-requests per step (the R0-R9 evidence
// says the step clock is LLC request-rate, not serialized RTTs).

__device__ inline float sig_f(float x) { return 1.f / (1.f + __expf(-x)); }
__device__ inline float tanh_f(float x) {
  float t = __expf(-2.f * fabsf(x));
  return copysignf((1.f - t) / (1.f + t), x);
}
__device__ inline unsigned umin_(unsigned a, unsigned b) { return a < b ? a : b; }

// ---- LLC-coherent (agent-scope) accessors — proven R3/R4/R8 ----
__device__ inline void cstore_pair(_Float16* p, float a, float b) {
  union { unsigned u; _Float16 h[2]; } pk;
  pk.h[0] = (_Float16)a; pk.h[1] = (_Float16)b;
  __hip_atomic_store((unsigned*)p, pk.u, __ATOMIC_RELAXED, __HIP_MEMORY_SCOPE_AGENT);
}
__device__ inline void cstore64(_Float16* p, u64 v) {
  __hip_atomic_store((u64*)p, v, __ATOMIC_RELAXED, __HIP_MEMORY_SCOPE_AGENT);
}
__device__ inline u64 cload64(const _Float16* p) {
  return __hip_atomic_load((const u64*)p, __ATOMIC_RELAXED, __HIP_MEMORY_SCOPE_AGENT);
}
__device__ inline half8 cload_h8(const _Float16* p) {
  union { u64 u[2]; half8 v; } r;
  r.u[0] = cload64(p);
  r.u[1] = cload64(p + 4);
  return r.v;
}

// Coalesced fragment-linear load: 16 frags, 4 base pointers (offset imm <=
// 4095), one waitcnt. b0 = snapshot + wv*16384 + lane*16 (bytes).
__device__ inline void ldfrag16(const char* b0, half8 (&r)[16]) {
  const char* b1 = b0 + 4096;
  const char* b2 = b0 + 8192;
  const char* b3 = b0 + 12288;
  floatx4 t0, t1, t2, t3, t4, t5, t6, t7, t8, t9, t10, t11, t12, t13, t14, t15;
  asm volatile(
      "global_load_dwordx4 %0, %16, off sc0 sc1\n\t"
      "global_load_dwordx4 %1, %16, off offset:1024 sc0 sc1\n\t"
      "global_load_dwordx4 %2, %16, off offset:2048 sc0 sc1\n\t"
      "global_load_dwordx4 %3, %16, off offset:3072 sc0 sc1\n\t"
      "global_load_dwordx4 %4, %17, off sc0 sc1\n\t"
      "global_load_dwordx4 %5, %17, off offset:1024 sc0 sc1\n\t"
      "global_load_dwordx4 %6, %17, off offset:2048 sc0 sc1\n\t"
      "global_load_dwordx4 %7, %17, off offset:3072 sc0 sc1\n\t"
      "global_load_dwordx4 %8, %18, off sc0 sc1\n\t"
      "global_load_dwordx4 %9, %18, off offset:1024 sc0 sc1\n\t"
      "global_load_dwordx4 %10, %18, off offset:2048 sc0 sc1\n\t"
      "global_load_dwordx4 %11, %18, off offset:3072 sc0 sc1\n\t"
      "global_load_dwordx4 %12, %19, off sc0 sc1\n\t"
      "global_load_dwordx4 %13, %19, off offset:1024 sc0 sc1\n\t"
      "global_load_dwordx4 %14, %19, off offset:2048 sc0 sc1\n\t"
      "global_load_dwordx4 %15, %19, off offset:3072 sc0 sc1\n\t"
      "s_waitcnt vmcnt(0)"
      : "=&v"(t0), "=&v"(t1), "=&v"(t2), "=&v"(t3),
        "=&v"(t4), "=&v"(t5), "=&v"(t6), "=&v"(t7),
        "=&v"(t8), "=&v"(t9), "=&v"(t10), "=&v"(t11),
        "=&v"(t12), "=&v"(t13), "=&v"(t14), "=&v"(t15)
      : "v"(b0), "v"(b1), "v"(b2), "v"(b3)
      : "memory");
  r[0] = __builtin_bit_cast(half8, t0);   r[1] = __builtin_bit_cast(half8, t1);
  r[2] = __builtin_bit_cast(half8, t2);   r[3] = __builtin_bit_cast(half8, t3);
  r[4] = __builtin_bit_cast(half8, t4);   r[5] = __builtin_bit_cast(half8, t5);
  r[6] = __builtin_bit_cast(half8, t6);   r[7] = __builtin_bit_cast(half8, t7);
  r[8] = __builtin_bit_cast(half8, t8);   r[9] = __builtin_bit_cast(half8, t9);
  r[10] = __builtin_bit_cast(half8, t10); r[11] = __builtin_bit_cast(half8, t11);
  r[12] = __builtin_bit_cast(half8, t12); r[13] = __builtin_bit_cast(half8, t13);
  r[14] = __builtin_bit_cast(half8, t14); r[15] = __builtin_bit_cast(half8, t15);
}

// Wave-parallel wait: lane i min-reduces block i's 4 per-wave sub-flags (16B).
__device__ inline void waitf4(const unsigned* fg, unsigned tg) {
  if (tg == 0) return;
  const unsigned* p = fg + (threadIdx.x & 63) * 32;
  int it = 0;
  for (;;) {
    floatx4 t;
    asm volatile("global_load_dwordx4 %0, %1, off sc0 sc1\n\t"
                 "s_waitcnt vmcnt(0)"
                 : "=&v"(t) : "v"(p) : "memory");
    uintx4 u = __builtin_bit_cast(uintx4, t);
    unsigned m = umin_(umin_(u.x, u.y), umin_(u.z, u.w));
    if (__all((int)(m >= tg))) return;
    if (++it > 4) __builtin_amdgcn_s_sleep(1);
  }
}

// Poll fg1 until >= tg1 while also sampling fg0 >= tg0 in the same pipelined
// round. Returns whether fg0 held on the final iteration (R8-proven skip).
__device__ inline bool waitf4_dual(const unsigned* fg1, unsigned tg1,
                                   const unsigned* fg0, unsigned tg0) {
  const unsigned* p1 = fg1 + (threadIdx.x & 63) * 32;
  const unsigned* p0 = fg0 + (threadIdx.x & 63) * 32;
  unsigned m1, m0v;
  int it = 0;
  for (;;) {
    floatx4 t1, t0;
    asm volatile("global_load_dwordx4 %0, %2, off sc0 sc1\n\t"
                 "global_load_dwordx4 %1, %3, off sc0 sc1\n\t"
                 "s_waitcnt vmcnt(0)"
                 : "=&v"(t1), "=&v"(t0)
                 : "v"(p1), "v"(p0)
                 : "memory");
    uintx4 u1 = __builtin_bit_cast(uintx4, t1);
    uintx4 u0 = __builtin_bit_cast(uintx4, t0);
    m1 = umin_(umin_(u1.x, u1.y), umin_(u1.z, u1.w));
    m0v = umin_(umin_(u0.x, u0.y), umin_(u0.z, u0.w));
    if (__all((int)(m1 >= tg1))) break;
    if (++it > 4) __builtin_amdgcn_s_sleep(1);
  }
  return (bool)__all((int)(m0v >= tg0));
}

__device__ inline floatx4 mfma16(half8 a, half8 b, floatx4 c) {
  return __builtin_amdgcn_mfma_f32_16x16x32_f16(a, b, c, 0, 0, 0);
}

__global__ void init_kernel(const float* __restrict__ x, const float* __restrict__ hc,
                            _Float16* __restrict__ x16, _Float16* __restrict__ h0b,
                            _Float16* __restrict__ h1b, unsigned* __restrict__ flagbase) {
  size_t i = (size_t)blockIdx.x * blockDim.x + threadIdx.x;
  size_t stride = (size_t)gridDim.x * blockDim.x;
  // x -> frag-linear fp16: chunk n = (t*64+row)*32 + cc covers cols 8cc..8cc+7.
  const size_t nch = (size_t)T_STEPS * 64 * 32;
  for (size_t n = i; n < nch; n += stride) {
    size_t tr = n >> 5;          // t*64+row
    int cc = (int)(n & 31);
    int row = (int)(tr & 63);
    size_t t = tr >> 6;
    const float* src = x + (tr * 256 + (size_t)cc * 8);
    floatx4 v0 = *(const floatx4*)src;
    floatx4 v1 = *(const floatx4*)(src + 4);
    half8 h;
    h[0] = (_Float16)v0.x; h[1] = (_Float16)v0.y; h[2] = (_Float16)v0.z; h[3] = (_Float16)v0.w;
    h[4] = (_Float16)v1.x; h[5] = (_Float16)v1.y; h[6] = (_Float16)v1.z; h[7] = (_Float16)v1.w;
    _Float16* dstp = x16 + t * 16384 + (size_t)(row >> 4) * 4096 +
                     (size_t)(cc >> 2) * 512 + (size_t)((row & 15) + 16 * (cc & 3)) * 8;
    *(half8*)dstp = h;
  }
  // h seeds in frag-linear layout (agent-scope stores; consumers use sc1 loads).
  if (i < 8192) {
    int which = (int)(i >> 12);          // 0: h0 seed, 1: h1 seed
    int idx = (int)(i & 4095);           // 64 rows x 64 chunks
    int m = idx >> 6, cc = idx & 63;
    const float* src = hc + (size_t)which * 32768 + (size_t)m * 512 + (size_t)cc * 8;
    union { u64 u[2]; half8 v; } pk;
#pragma unroll
    for (int e = 0; e < 8; ++e) pk.v[e] = (_Float16)src[e];
    _Float16* base = which ? (h1b + 32768) : (h0b + (size_t)(RING - 1) * 32768);
    _Float16* dstp = base + (size_t)(m >> 4) * 8192 + (size_t)(cc >> 2) * 512 +
                     (size_t)((m & 15) + 16 * (cc & 3)) * 8;
    cstore64(dstp, pk.u[0]);
    cstore64(dstp + 4, pk.u[1]);
  }
  if (i < 4096) {  // zero both flag arrays (2 x 8192 B contiguous)
    __hip_atomic_store(flagbase + i, 0u, __ATOMIC_RELAXED, __HIP_MEMORY_SCOPE_AGENT);
  }
}

__global__ __launch_bounds__(256, 1) void lstm_kernel(
    const _Float16* __restrict__ x16, _Float16* __restrict__ h0b, _Float16* __restrict__ h1b,
    unsigned* __restrict__ flags0, unsigned* __restrict__ flags1,
    const float* __restrict__ W_ih0, const float* __restrict__ W_hh0,
    const float* __restrict__ b_ih0, const float* __restrict__ b_hh0,
    const float* __restrict__ W_ih1, const float* __restrict__ W_hh1,
    const float* __restrict__ b_ih1, const float* __restrict__ b_hh1,
    const float* __restrict__ W_out, const float* __restrict__ b_out,
    const float* __restrict__ hc, float* __restrict__ out) {
  __shared__ __align__(16) _Float16 wlds[32 * 1032];

  const int bq = blockIdx.x;
  const bool isL0 = bq < 64;
  const int q = isL0 ? bq : bq - 64;
  const int col0 = q * 8;
  const int Ka = isL0 ? IN_DIM : HID;
  const int K = Ka + HID;
  const int WP = K + 8;
  const int layer = isL0 ? 0 : 1;
  const float* Wa = isL0 ? W_ih0 : W_ih1;
  const float* Wb = isL0 ? W_hh0 : W_hh1;
  const float* bia = isL0 ? b_ih0 : b_ih1;
  const float* bib = isL0 ? b_hh0 : b_hh1;

  for (int idx = threadIdx.x; idx < 32 * K; idx += 256) {
    int r = idx / K;
    int k = idx - r * K;
    int g = r >> 3, j = r & 7;
    int grow = g * HID + col0 + j;  // PyTorch gate order i,f,g,o
    float w = (k < Ka) ? Wa[(size_t)grow * Ka + k] : Wb[(size_t)grow * HID + (k - Ka)];
    wlds[r * WP + k] = (_Float16)w;
  }
  __syncthreads();

  const int lane = threadIdx.x & 63;
  const int wv = threadIdx.x >> 6;   // 0..3
  const int lrow = lane & 15;
  const int kq = (lane >> 4) * 8;
  const int m0 = wv * 16;
  const _Float16* wrow0 = wlds + lrow * WP;
  const _Float16* wrow1 = wlds + (16 + lrow) * WP;

  // Recurrent-half B fragments in registers/AGPRs (proven R2/R3).
  half8 breg0[16], breg1[16];
#pragma unroll
  for (int c = 0; c < 16; ++c) {
    breg0[c] = *(const half8*)(wrow0 + Ka + c * 32 + kq);
    breg1[c] = *(const half8*)(wrow1 + Ka + c * 32 + kq);
  }

  // Register-gate-phase constants (R8-proven mapping).
  const int bsel = lrow >> 3;
  const int jc = lrow & 7;
  const int rbase = m0 + ((lane >> 4) << 2) + 2 * bsel;
  const int colg = col0 + jc;
  const float bi_ = bia[colg] + bib[colg];
  const float bf_ = bia[HID + colg] + bib[HID + colg];
  const float bg_ = bia[2 * HID + colg] + bib[2 * HID + colg];
  const float bo_ = bia[3 * HID + colg] + bib[3 * HID + colg];
  float cst0 = hc[(size_t)(2 + layer) * 32768 + (size_t)(rbase + 0) * HID + colg];
  float cst1 = hc[(size_t)(2 + layer) * 32768 + (size_t)(rbase + 1) * HID + colg];

  unsigned* myflag = (isL0 ? flags0 : flags1) + q * 32 + wv;

  // Frag-linear per-lane offsets.
  const size_t rd_off = (size_t)wv * 16384 + (size_t)lane * 16;  // bytes
  // Store slot: l = (rbase&15) + 16*(q&3), frag = q>>2, byte-in-chunk = 2*jc.
  const size_t st_off = (size_t)wv * 8192 + (size_t)(q >> 2) * 512 +
                        (size_t)((rbase & 15) + ((q & 3) << 4)) * 8 + jc;  // halfwords

  bool skip0 = false;  // L1: mid-step dual-poll saw flags0 >= t+2 (R8-proven)

  for (int t = 0; t < T_STEPS; ++t) {
    floatx4 acc0 = {0.f, 0.f, 0.f, 0.f};
    floatx4 acc1 = {0.f, 0.f, 0.f, 0.f};
    _Float16* dst;
    half8 f[16];

    if (isL0) {
      // X phase (no cross-block dep): coalesced frag-linear plain loads.
      const _Float16* xw = x16 + (size_t)t * 16384 + (size_t)wv * 4096 + (size_t)lane * 8;
#pragma unroll
      for (int c = 0; c < 8; ++c) {
        half8 a = *(const half8*)(xw + c * 512);
        half8 b0v = *(const half8*)(wrow0 + c * 32 + kq);
        half8 b1v = *(const half8*)(wrow1 + c * 32 + kq);
        acc0 = mfma16(a, b0v, acc0);
        acc1 = mfma16(a, b1v, acc1);
      }
      // Merged wait: wave0 -> peers' h0[t-1]; wave1 -> ring slot free.
      if (threadIdx.x < 64) waitf4(flags0, (unsigned)t);
      else if (threadIdx.x < 128) waitf4(flags1, (t >= RING) ? (unsigned)(t - RING + 1) : 0u);
      __syncthreads();
      asm volatile("" ::: "memory");
      const char* a1p = (const char*)(h0b + (size_t)((t - 1) & (RING - 1)) * 32768) + rd_off;
      ldfrag16(a1p, f);
#pragma unroll
      for (int c = 0; c < 16; ++c) {
        acc0 = mfma16(f[c], breg0[c], acc0);
        acc1 = mfma16(f[c], breg1[c], acc1);
      }
      dst = h0b + (size_t)(t & (RING - 1)) * 32768;
    } else {
      if (threadIdx.x < 64 && !skip0) waitf4(flags0, (unsigned)(t + 1));  // h0[t] ready
      __syncthreads();
      asm volatile("" ::: "memory");
      const char* a0p = (const char*)(h0b + (size_t)(t & (RING - 1)) * 32768) + rd_off;
      ldfrag16(a0p, f);
#pragma unroll
      for (int c = 0; c < 16; ++c) {
        half8 b0v = *(const half8*)(wrow0 + c * 32 + kq);
        half8 b1v = *(const half8*)(wrow1 + c * 32 + kq);
        acc0 = mfma16(f[c], b0v, acc0);
        acc1 = mfma16(f[c], b1v, acc1);
      }
      // flags1 wait AFTER the h0 phase (R4/R8-proven placement); same round
      // samples flags0>=t+2 so next step's top wait is usually skipped.
      if (threadIdx.x < 64)
        skip0 = waitf4_dual(flags1, (unsigned)t, flags0, (unsigned)(t + 2));
      __syncthreads();
      asm volatile("" ::: "memory");
      const char* a1p = (const char*)(h1b + (size_t)((t - 1) & 1) * 32768) + rd_off;
      ldfrag16(a1p, f);
#pragma unroll
      for (int c = 0; c < 16; ++c) {
        acc0 = mfma16(f[c], breg0[c], acc0);
        acc1 = mfma16(f[c], breg1[c], acc1);
      }
      dst = h1b + (size_t)(t & 1) * 32768;
    }

    // ---- register gate phase (R8-proven) ----
    float s00 = __shfl_xor(bsel ? (float)acc0[0] : (float)acc0[2], 8);
    float s01 = __shfl_xor(bsel ? (float)acc0[1] : (float)acc0[3], 8);
    float s10 = __shfl_xor(bsel ? (float)acc1[0] : (float)acc1[2], 8);
    float s11 = __shfl_xor(bsel ? (float)acc1[1] : (float)acc1[3], 8);
    float hv0, hv1;
    {
      float o0 = bsel ? (float)acc0[2] : (float)acc0[0];
      float o1 = bsel ? (float)acc1[2] : (float)acc1[0];
      float gi = bsel ? s00 : o0;
      float gf = bsel ? o0 : s00;
      float gg = bsel ? s10 : o1;
      float go = bsel ? o1 : s10;
      float c = sig_f(gf + bf_) * cst0 + sig_f(gi + bi_) * tanh_f(gg + bg_);
      cst0 = c;
      hv0 = sig_f(go + bo_) * tanh_f(c);
    }
    {
      float o0 = bsel ? (float)acc0[3] : (float)acc0[1];
      float o1 = bsel ? (float)acc1[3] : (float)acc1[1];
      float gi = bsel ? s01 : o0;
      float gf = bsel ? o0 : s01;
      float gg = bsel ? s11 : o1;
      float go = bsel ? o1 : s11;
      float c = sig_f(gf + bf_) * cst1 + sig_f(gi + bi_) * tanh_f(gg + bg_);
      cst1 = c;
      hv1 = sig_f(go + bo_) * tanh_f(c);
    }
    // Pack adjacent columns (lane^1) so even-jc lanes store 4B pairs into the
    // frag-linear slots; row rbase+1 is +8 halfwords (l+1).
    float hx0 = __shfl_xor(hv0, 1);
    float hx1 = __shfl_xor(hv1, 1);
    if ((jc & 1) == 0) {
      _Float16* sb = dst + st_off;
      cstore_pair(sb, hv0, hx0);
      cstore_pair(sb + 8, hv1, hx1);
    }

    // Release: per-wave drain + per-wave sub-flag; no block barrier (each
    // wave's future reads touch only rows it wrote itself) — R8-proven.
    asm volatile("s_waitcnt vmcnt(0)" ::: "memory");
    if ((threadIdx.x & 63) == 0) {
      __hip_atomic_store(myflag, (unsigned)(t + 1), __ATOMIC_RELAXED,
                         __HIP_MEMORY_SCOPE_AGENT);
    }
    asm volatile("" ::: "memory");
  }

  // Final linear on L0 blocks: out[64,256] = h1[511] @ W_out^T + b_out.
  if (isL0) {
    if (threadIdx.x < 64) waitf4(flags1, (unsigned)T_STEPS);
    __syncthreads();
    asm volatile("" ::: "memory");
    const int oc = q * 4 + (threadIdx.x & 3);
    const int m = threadIdx.x >> 2;
    const float* wrow = W_out + (size_t)oc * HID;
    const _Float16* hbase = h1b + 32768;  // h1[511] at parity 1, frag-linear
    float sum = 0.f;
#pragma unroll 4
    for (int hh = 0; hh < 64; ++hh) {  // chunk hh = cols 8hh..8hh+7
      const _Float16* cp = hbase + (size_t)(m >> 4) * 8192 + (size_t)(hh >> 2) * 512 +
                           (size_t)((m & 15) + 16 * (hh & 3)) * 8;
      half8 hvv = cload_h8(cp);
#pragma unroll
      for (int e = 0; e < 8; ++e) sum += (float)hvv[e] * wrow[hh * 8 + e];
    }
    out[m * 256 + oc] = sum + b_out[oc];
  }
}

extern "C" void kernel_launch(void* const* d_in, const int* in_sizes, int n_in,
                              void* d_out, int out_size, void* d_ws, size_t ws_size,
                              hipStream_t stream) {
  const float* x     = (const float*)d_in[0];
  const float* hc    = (const float*)d_in[1];
  const float* W_ih0 = (const float*)d_in[2];
  const float* W_hh0 = (const float*)d_in[3];
  const float* b_ih0 = (const float*)d_in[4];
  const float* b_hh0 = (const float*)d_in[5];
  const float* W_ih1 = (const float*)d_in[6];
  const float* W_hh1 = (const float*)d_in[7];
  const float* b_ih1 = (const float*)d_in[8];
  const float* b_hh1 = (const float*)d_in[9];
  const float* W_out = (const float*)d_in[10];
  const float* b_out = (const float*)d_in[11];
  float* out = (float*)d_out;

  char* ws = (char*)d_ws;
  _Float16* x16 = (_Float16*)ws;                              // 16 MB (frag-linear)
  _Float16* h0b = (_Float16*)(ws + 16777216);                 // 8 x 64 KB ring
  _Float16* h1b = (_Float16*)(ws + 16777216 + 8 * 65536);     // 2 x 64 KB
  unsigned* flags0 = (unsigned*)(ws + 16777216 + 10 * 65536);           // 8 KB
  unsigned* flags1 = (unsigned*)(ws + 16777216 + 10 * 65536 + 8192);    // 8 KB

  init_kernel<<<2048, 256, 0, stream>>>(x, hc, x16, h0b, h1b, flags0);
  lstm_kernel<<<128, 256, 0, stream>>>(x16, h0b, h1b, flags0, flags1,
                                       W_ih0, W_hh0, b_ih0, b_hh0,
                                       W_ih1, W_hh1, b_ih1, b_hh1,
                                       W_out, b_out, hc, out);
}